// Round 1
// baseline (5535.970 us; speedup 1.0000x reference)
//
#include <hip/hip_runtime.h>
#include <cstdint>
#include <cstddef>

#define Hn 256
#define Sn 2048
#define Bn 128
#define NR 768

typedef _Float16 half2_t __attribute__((ext_vector_type(2)));

__device__ __forceinline__ float fdot2_(half2_t a, half2_t b, float c){
#if __has_builtin(__builtin_amdgcn_fdot2)
  return __builtin_amdgcn_fdot2(a, b, c, false);
#else
  float d;
  asm volatile("v_dot2_f32_f16 %0, %1, %2, %3" : "=v"(d) : "v"(a), "v"(b), "v"(c));
  return d;
#endif
}

__device__ __forceinline__ float sigmoid_(float v){ return 1.0f/(1.0f+__expf(-v)); }
__device__ __forceinline__ float tanh_(float v){
  float e = __expf(-2.0f*__builtin_fabsf(v));
  float r = (1.0f-e)/(1.0f+e);
  return __builtin_copysignf(r, v);
}

// One workgroup per batch element (128 WGs x 768 threads = 12 waves).
// Thread t owns gate row t of w_hh (256 f16 weights register-resident, 128 VGPRs).
// h broadcast via LDS as packed f16; dot via v_dot2_f32_f16 (fp32 accumulate).
__global__ void __launch_bounds__(768)
bio_rnn(const float* __restrict__ x,
        const float* __restrict__ w_ih, const float* __restrict__ w_hh,
        const float* __restrict__ b_ih, const float* __restrict__ b_hh,
        const float* __restrict__ w_gain, const float* __restrict__ b_gain,
        const float* __restrict__ w_bias, const float* __restrict__ b_bias,
        const float* __restrict__ w_reflex, const float* __restrict__ b_reflex,
        const float* __restrict__ w_policy, const float* __restrict__ b_policy,
        const float* __restrict__ w_motor, const float* __restrict__ b_motor,
        float* __restrict__ y_out, float* __restrict__ router)
{
  const int b = blockIdx.x;
  const int t = threadIdx.x;

  __shared__ __align__(16) half2_t hpk[Hn/2];   // h packed f16
  __shared__ float A[NR];                        // gi+gh (rows<512) or gh (n-rows)
  __shared__ float GIN[Hn];                      // gi for n-rows
  __shared__ float RED[4][8];                    // wave-reduction scratch
  __shared__ float Gg[2], Bb[4];
  __shared__ float HW[13][Hn];                   // head weights (saves VGPRs)

  // ---- one-time: register-cache w_hh row t as f16 pairs ----
  half2_t w[128];
  {
    const float* wr = w_hh + (size_t)t * Hn;
    #pragma unroll
    for (int k = 0; k < 128; k++){
      half2_t v; v.x = (_Float16)wr[2*k]; v.y = (_Float16)wr[2*k+1];
      w[k] = v;
    }
  }
  float wih[6];
  #pragma unroll
  for (int d = 0; d < 6; d++) wih[d] = w_ih[t*6 + d];
  const float bih = b_ih[t], bhh = b_hh[t];

  if (t < Hn){
    HW[0][t] = w_gain[t];        HW[1][t]  = w_gain[Hn + t];
    HW[2][t] = w_bias[t];        HW[3][t]  = w_bias[Hn + t];
    HW[4][t] = w_bias[2*Hn + t]; HW[5][t]  = w_bias[3*Hn + t];
    HW[6][t] = w_reflex[2*t];    HW[7][t]  = w_reflex[2*t + 1];
    HW[8][t] = b_reflex[t];
    HW[9][t] = w_policy[t];      HW[10][t] = w_policy[Hn + t];
    HW[11][t] = w_motor[t];      HW[12][t] = w_motor[Hn + t];
  }
  if (t < Hn/2){ half2_t z0; z0.x = (_Float16)0.f; z0.y = (_Float16)0.f; hpk[t] = z0; }
  float hreg = 0.f;

  float bsm = 0.f;                       // per-thread small bias (t<6)
  if (t < 2) bsm = b_gain[t];
  else if (t < 6) bsm = b_bias[t-2];
  float bp0=0.f, bp1=0.f, bm0=0.f, bm1=0.f;
  if (t == 0){ bp0 = b_policy[0]; bp1 = b_policy[1]; bm0 = b_motor[0]; bm1 = b_motor[1]; }
  __syncthreads();

  const float* xp = x + (size_t)b * Sn * 6;
  float* rout = router + (size_t)b * Sn * Hn + t;
  float* yo   = y_out  + (size_t)b * Sn * 4;

  for (int s = 0; s < Sn; s++){
    // block-uniform x load (scalarizes to s_load)
    const float x0=xp[0], x1=xp[1], x2=xp[2], x3=xp[3], x4=xp[4], x5=xp[5];
    float gi = bih + wih[0]*x0 + wih[1]*x1 + wih[2]*x2
                   + wih[3]*x3 + wih[4]*x4 + wih[5]*x5;

    // gh row-t dot: 128 x v_dot2_f32_f16, 4 independent accumulator chains
    float a0 = bhh, a1 = 0.f, a2 = 0.f, a3 = 0.f;
    const uint4* hv4 = (const uint4*)hpk;
    #pragma unroll
    for (int k = 0; k < 32; k++){
      uint4 hv = hv4[k];                    // ds_read_b128, uniform addr (broadcast)
      a0 = fdot2_(w[4*k+0], __builtin_bit_cast(half2_t, hv.x), a0);
      a1 = fdot2_(w[4*k+1], __builtin_bit_cast(half2_t, hv.y), a1);
      a2 = fdot2_(w[4*k+2], __builtin_bit_cast(half2_t, hv.z), a2);
      a3 = fdot2_(w[4*k+3], __builtin_bit_cast(half2_t, hv.w), a3);
    }
    float acc = (a0 + a1) + (a2 + a3);
    if (t < 512) A[t] = gi + acc;
    else { A[t] = acc; GIN[t - 512] = gi; }
    __syncthreads();                                        // B1

    if (t < Hn){
      float r = sigmoid_(A[t]);
      float z = sigmoid_(A[t + Hn]);
      float n = tanh_(GIN[t] + r * A[t + 2*Hn]);
      float hnew = (1.f - z) * n + z * hreg;
      hreg = hnew;
      ((_Float16*)hpk)[t] = (_Float16)hnew;
      rout[(size_t)s * Hn] = hnew;                          // router_activity
      // gain/bias head partials (6 dots over h)
      float p0 = hnew*HW[0][t], p1 = hnew*HW[1][t], p2 = hnew*HW[2][t];
      float p3 = hnew*HW[3][t], p4 = hnew*HW[4][t], p5 = hnew*HW[5][t];
      #pragma unroll
      for (int off = 32; off >= 1; off >>= 1){
        p0 += __shfl_xor(p0, off); p1 += __shfl_xor(p1, off); p2 += __shfl_xor(p2, off);
        p3 += __shfl_xor(p3, off); p4 += __shfl_xor(p4, off); p5 += __shfl_xor(p5, off);
      }
      if ((t & 63) == 0){
        const int wv = t >> 6;
        RED[wv][0]=p0; RED[wv][1]=p1; RED[wv][2]=p2;
        RED[wv][3]=p3; RED[wv][4]=p4; RED[wv][5]=p5;
      }
    }
    __syncthreads();                                        // B2
    if (t < 6){
      float v = RED[0][t] + RED[1][t] + RED[2][t] + RED[3][t] + bsm;
      if (t < 2) Gg[t] = sigmoid_(v);
      else Bb[t-2] = v;
    }
    __syncthreads();                                        // B3
    if (t < Hn){
      float u0 = x0 * Gg[0], u1 = x1 * Gg[1];
      float f = u0*HW[6][t] + u1*HW[7][t] + HW[8][t];
      f = fmaxf(f, 0.f);                                    // feat
      float q0 = f*HW[9][t], q1 = f*HW[10][t], q2 = f*HW[11][t], q3 = f*HW[12][t];
      #pragma unroll
      for (int off = 32; off >= 1; off >>= 1){
        q0 += __shfl_xor(q0, off); q1 += __shfl_xor(q1, off);
        q2 += __shfl_xor(q2, off); q3 += __shfl_xor(q3, off);
      }
      if ((t & 63) == 0){
        const int wv = t >> 6;
        RED[wv][0]=q0; RED[wv][1]=q1; RED[wv][2]=q2; RED[wv][3]=q3;
      }
    }
    __syncthreads();                                        // B4
    if (t == 0){
      float s0 = RED[0][0]+RED[1][0]+RED[2][0]+RED[3][0];
      float s1 = RED[0][1]+RED[1][1]+RED[2][1]+RED[3][1];
      float s2 = RED[0][2]+RED[1][2]+RED[2][2]+RED[3][2];
      float s3 = RED[0][3]+RED[1][3]+RED[2][3]+RED[3][3];
      float4 o;
      o.x = s0 + bp0 + Bb[0];
      o.y = s1 + bp1 + Bb[1];
      o.z = tanh_(s2 + bm0 + Bb[2]);
      o.w = tanh_(s3 + bm1 + Bb[3]);
      *(float4*)(yo + (size_t)s * 4) = o;
    }
    xp += 6;
  }
}

extern "C" void kernel_launch(void* const* d_in, const int* in_sizes, int n_in,
                              void* d_out, int out_size, void* d_ws, size_t ws_size,
                              hipStream_t stream)
{
  const float* x        = (const float*)d_in[0];
  const float* w_ih     = (const float*)d_in[1];
  const float* w_hh     = (const float*)d_in[2];
  const float* b_ih     = (const float*)d_in[3];
  const float* b_hh     = (const float*)d_in[4];
  const float* w_gain   = (const float*)d_in[5];
  const float* b_gain   = (const float*)d_in[6];
  const float* w_bias   = (const float*)d_in[7];
  const float* b_bias   = (const float*)d_in[8];
  const float* w_reflex = (const float*)d_in[9];
  const float* b_reflex = (const float*)d_in[10];
  const float* w_policy = (const float*)d_in[11];
  const float* b_policy = (const float*)d_in[12];
  const float* w_motor  = (const float*)d_in[13];
  const float* b_motor  = (const float*)d_in[14];

  float* y_out  = (float*)d_out;
  float* router = (float*)d_out + (size_t)Bn * Sn * 4;

  bio_rnn<<<dim3(Bn), dim3(NR), 0, stream>>>(
      x, w_ih, w_hh, b_ih, b_hh, w_gain, b_gain, w_bias, b_bias,
      w_reflex, b_reflex, w_policy, b_policy, w_motor, b_motor,
      y_out, router);
}